// Round 1
// baseline (158.931 us; speedup 1.0000x reference)
//
#include <hip/hip_runtime.h>
#include <cmath>

#define NQ 12
#define DIM (1 << NQ)      // 4096 amplitudes
#define NL 4
#define NBATCH 1024
#define BLOCK 256

// One block = one batch element. State lives in LDS as separate re/im arrays.
// Every gate pass: each thread owns disjoint (i0,i1) pairs -> no intra-pass
// races; __syncthreads() between passes.
__global__ __launch_bounds__(BLOCK) void vqc_kernel(
    const float* __restrict__ x,      // (1024, 12)
    const float* __restrict__ wts,    // (4, 12, 3)
    float* __restrict__ out)          // (1024, 12)
{
    __shared__ float sre[DIM];
    __shared__ float sim[DIM];
    __shared__ float gmat[NL * NQ][8];   // Rot gates: (g00,g01,g10,g11) as re,im pairs
    __shared__ float rxg[NQ][2];         // RX per wire: cos(x/2), sin(x/2)
    __shared__ float red[BLOCK / 64][NQ];

    const int b = blockIdx.x;
    const int tid = threadIdx.x;

    // ---- init |0...0> ----
    for (int i = tid; i < DIM; i += BLOCK) { sre[i] = 0.f; sim[i] = 0.f; }
    if (tid == 0) sre[0] = 1.f;

    // ---- precompute gate coefficients ----
    if (tid < NQ) {
        float h = 0.5f * x[b * NQ + tid];
        rxg[tid][0] = cosf(h);
        rxg[tid][1] = sinf(h);
    }
    if (tid < NL * NQ) {
        float phi = wts[tid * 3 + 0];
        float th  = wts[tid * 3 + 1];
        float om  = wts[tid * 3 + 2];
        float ct = cosf(0.5f * th), sn = sinf(0.5f * th);
        float sp, cp, sd, cd;
        sincosf(0.5f * (phi + om), &sp, &cp);
        sincosf(0.5f * (phi - om), &sd, &cd);
        // Rot = [[em*ct, -ed*sn], [edc*sn, ep*ct]]
        // em=(cp,-sp) ep=(cp,sp) ed=(cd,sd) edc=(cd,-sd)
        gmat[tid][0] =  cp * ct;  gmat[tid][1] = -sp * ct;   // g00
        gmat[tid][2] = -cd * sn;  gmat[tid][3] = -sd * sn;   // g01
        gmat[tid][4] =  cd * sn;  gmat[tid][5] = -sd * sn;   // g10
        gmat[tid][6] =  cp * ct;  gmat[tid][7] =  sp * ct;   // g11
    }
    __syncthreads();

    // ---- 1-qubit gate on wire q (bit position NQ-1-q, stride S) ----
    auto apply1q = [&](int q, float g00r, float g00i, float g01r, float g01i,
                               float g10r, float g10i, float g11r, float g11i) {
        const int S = 1 << (NQ - 1 - q);
        #pragma unroll
        for (int t = tid; t < DIM / 2; t += BLOCK) {
            int i0 = ((t & ~(S - 1)) << 1) | (t & (S - 1));
            int i1 = i0 | S;
            float a0r = sre[i0], a0i = sim[i0];
            float a1r = sre[i1], a1i = sim[i1];
            sre[i0] = g00r * a0r - g00i * a0i + g01r * a1r - g01i * a1i;
            sim[i0] = g00r * a0i + g00i * a0r + g01r * a1i + g01i * a1r;
            sre[i1] = g10r * a0r - g10i * a0i + g11r * a1r - g11i * a1i;
            sim[i1] = g10r * a0i + g10i * a0r + g11r * a1i + g11i * a1r;
        }
        __syncthreads();
    };

    // ---- CNOT(control c, target t): swap amplitudes where ctrl=1, tgt flips ----
    auto cnot = [&](int c, int t) {
        const int pc = NQ - 1 - c, pt = NQ - 1 - t;
        const int plo = pc < pt ? pc : pt;
        const int phi_ = pc < pt ? pt : pc;
        const int Sc = 1 << pc, St = 1 << pt;
        #pragma unroll
        for (int k = tid; k < DIM / 4; k += BLOCK) {
            int low  = k & ((1 << plo) - 1);
            int mid  = (k >> plo) & ((1 << (phi_ - plo - 1)) - 1);
            int high = k >> (phi_ - 1);
            int i = (high << (phi_ + 1)) | (mid << (plo + 1)) | low | Sc; // ctrl=1, tgt=0
            int j = i | St;
            float tr = sre[i], ti = sim[i];
            sre[i] = sre[j]; sim[i] = sim[j];
            sre[j] = tr;     sim[j] = ti;
        }
        __syncthreads();
    };

    // ---- AngleEmbedding: RX(x[b,q]) on each wire ----
    for (int q = 0; q < NQ; ++q) {
        float c = rxg[q][0], s = rxg[q][1];
        // RX = [[c, -i s], [-i s, c]]
        apply1q(q, c, 0.f, 0.f, -s, 0.f, -s, c, 0.f);
    }

    // ---- StronglyEntanglingLayers ----
    for (int l = 0; l < NL; ++l) {
        for (int q = 0; q < NQ; ++q) {
            const float* g = gmat[l * NQ + q];
            apply1q(q, g[0], g[1], g[2], g[3], g[4], g[5], g[6], g[7]);
        }
        int r = l % (NQ - 1) + 1;
        for (int q = 0; q < NQ; ++q) cnot(q, (q + r) % NQ);
    }

    // ---- <Z_q> = sum_i |amp_i|^2 * (bit_q(i)==0 ? +1 : -1) ----
    float ev[NQ];
    #pragma unroll
    for (int q = 0; q < NQ; ++q) ev[q] = 0.f;
    for (int i = tid; i < DIM; i += BLOCK) {
        float p = sre[i] * sre[i] + sim[i] * sim[i];
        #pragma unroll
        for (int q = 0; q < NQ; ++q)
            ev[q] += ((i >> (NQ - 1 - q)) & 1) ? -p : p;
    }
    // wave reduce (64 lanes), then cross-wave via LDS
    #pragma unroll
    for (int q = 0; q < NQ; ++q)
        for (int off = 32; off > 0; off >>= 1)
            ev[q] += __shfl_down(ev[q], off);
    const int lane = tid & 63, wv = tid >> 6;
    if (lane == 0)
        for (int q = 0; q < NQ; ++q) red[wv][q] = ev[q];
    __syncthreads();
    if (tid < NQ)
        out[b * NQ + tid] = red[0][tid] + red[1][tid] + red[2][tid] + red[3][tid];
}

extern "C" void kernel_launch(void* const* d_in, const int* in_sizes, int n_in,
                              void* d_out, int out_size, void* d_ws, size_t ws_size,
                              hipStream_t stream) {
    const float* x   = (const float*)d_in[0];
    const float* wts = (const float*)d_in[1];
    float* out = (float*)d_out;
    vqc_kernel<<<dim3(NBATCH), dim3(BLOCK), 0, stream>>>(x, wts, out);
}

// Round 2
// 116.840 us; speedup vs baseline: 1.3602x; 1.3602x over previous
//
#include <hip/hip_runtime.h>
#include <cmath>

#define NQ 12
#define NL 4
#define NBATCH 1024
#define BLOCK 256

typedef float2 f2;

// State mapping: amplitude index i[11:0] = (wave[1:0] << 10) | (lane[5:0] << 4) | local[3:0]
// qubit q acts on bit p = 11-q:
//   q=0,1   -> wave bits 1,0   (LDS exchange)
//   q=2..7  -> lane bits 5..0  (shfl_xor)
//   q=8..11 -> local bits 3..0 (registers)

template<int P>
__device__ __forceinline__ void gate_local(float (&ar)[16], float (&ai)[16], const float* g)
{
    const float g00r=g[0],g00i=g[1],g01r=g[2],g01i=g[3],g10r=g[4],g10i=g[5],g11r=g[6],g11i=g[7];
#pragma unroll
    for (int r0 = 0; r0 < 16; ++r0) {
        if ((r0 & (1 << P)) == 0) {
            const int r1 = r0 | (1 << P);
            const float a0r=ar[r0],a0i=ai[r0],a1r=ar[r1],a1i=ai[r1];
            ar[r0]=g00r*a0r-g00i*a0i+g01r*a1r-g01i*a1i;
            ai[r0]=g00r*a0i+g00i*a0r+g01r*a1i+g01i*a1r;
            ar[r1]=g10r*a0r-g10i*a0i+g11r*a1r-g11i*a1i;
            ai[r1]=g10r*a0i+g10i*a0r+g11r*a1i+g11i*a1r;
        }
    }
}

template<int LB>
__device__ __forceinline__ void gate_lane(float (&ar)[16], float (&ai)[16], int lane, const float* g)
{
    const bool hi = (lane >> LB) & 1;
    // own coeff: hi? g11 : g00 ; partner coeff: hi? g10 : g01
    const float gar = hi ? g[6] : g[0];
    const float gai = hi ? g[7] : g[1];
    const float gbr = hi ? g[4] : g[2];
    const float gbi = hi ? g[5] : g[3];
#pragma unroll
    for (int r = 0; r < 16; ++r) {
        const float o_r = __shfl_xor(ar[r], 1 << LB, 64);
        const float o_i = __shfl_xor(ai[r], 1 << LB, 64);
        const float nr = gar*ar[r]-gai*ai[r]+gbr*o_r-gbi*o_i;
        const float ni = gar*ai[r]+gai*ar[r]+gbr*o_i+gbi*o_r;
        ar[r]=nr; ai[r]=ni;
    }
}

template<int WB>
__device__ __forceinline__ void gate_wave(float (&ar)[16], float (&ai)[16],
    f2 (*xb)[BLOCK], int tid, int wave, const float* g)
{
    const bool hi = (wave >> WB) & 1;
    const float gar = hi ? g[6] : g[0];
    const float gai = hi ? g[7] : g[1];
    const float gbr = hi ? g[4] : g[2];
    const float gbi = hi ? g[5] : g[3];
    __syncthreads();                       // previous consumers of xb done
#pragma unroll
    for (int r = 0; r < 16; ++r) xb[r][tid] = make_float2(ar[r], ai[r]);
    __syncthreads();
    const int pt = tid ^ (64 << WB);
#pragma unroll
    for (int r = 0; r < 16; ++r) {
        const f2 o = xb[r][pt];
        const float nr = gar*ar[r]-gai*ai[r]+gbr*o.x-gbi*o.y;
        const float ni = gar*ai[r]+gai*ar[r]+gbr*o.y+gbi*o.x;
        ar[r]=nr; ai[r]=ni;
    }
}

// CNOT: swap amplitudes i <-> i^(1<<PT) where bit PC of i is 1.
template<int PC,int PT>
__device__ __forceinline__ void cnot_gate(float (&ar)[16], float (&ai)[16],
    f2 (*xb)[BLOCK], int tid, int lane, int wave)
{
    if constexpr (PT < 4) {                       // target local
        if constexpr (PC < 4) {                   // control local: compile-time swaps
#pragma unroll
            for (int r = 0; r < 16; ++r) {
                if (((r >> PC) & 1) && !((r >> PT) & 1)) {
                    const int r2 = r | (1 << PT);
                    float t;
                    t=ar[r]; ar[r]=ar[r2]; ar[r2]=t;
                    t=ai[r]; ai[r]=ai[r2]; ai[r2]=t;
                }
            }
        } else {                                  // control lane/wave: uniform-per-thread cond
            const bool u = (PC < 10) ? (((lane >> (PC-4)) & 1) != 0)
                                     : (((wave >> (PC-10)) & 1) != 0);
            if (u) {
#pragma unroll
                for (int r = 0; r < 16; ++r) {
                    if (!((r >> PT) & 1)) {
                        const int r2 = r | (1 << PT);
                        float t;
                        t=ar[r]; ar[r]=ar[r2]; ar[r2]=t;
                        t=ai[r]; ai[r]=ai[r2]; ai[r2]=t;
                    }
                }
            }
        }
    } else if constexpr (PT < 10) {               // target lane: shuffle exchange
        constexpr int m = 1 << (PT-4);
        if constexpr (PC < 4) {                   // cond compile-time per reg -> all lanes shuffle
#pragma unroll
            for (int r = 0; r < 16; ++r) {
                if ((r >> PC) & 1) {
                    ar[r] = __shfl_xor(ar[r], m, 64);
                    ai[r] = __shfl_xor(ai[r], m, 64);
                }
            }
        } else {                                  // cond per-thread: shuffle all, select
            const bool u = (PC < 10) ? (((lane >> (PC-4)) & 1) != 0)
                                     : (((wave >> (PC-10)) & 1) != 0);
#pragma unroll
            for (int r = 0; r < 16; ++r) {
                const float tr = __shfl_xor(ar[r], m, 64);
                const float ti = __shfl_xor(ai[r], m, 64);
                ar[r] = u ? tr : ar[r];
                ai[r] = u ? ti : ai[r];
            }
        }
    } else {                                      // target wave: LDS exchange
        __syncthreads();
#pragma unroll
        for (int r = 0; r < 16; ++r) xb[r][tid] = make_float2(ar[r], ai[r]);
        __syncthreads();
        const int pt_ = tid ^ (64 << (PT-10));
        if constexpr (PC < 4) {
#pragma unroll
            for (int r = 0; r < 16; ++r) {
                if ((r >> PC) & 1) { const f2 o = xb[r][pt_]; ar[r]=o.x; ai[r]=o.y; }
            }
        } else {
            const bool u = (PC < 10) ? (((lane >> (PC-4)) & 1) != 0)
                                     : (((wave >> (PC-10)) & 1) != 0);
            if (u) {
#pragma unroll
                for (int r = 0; r < 16; ++r) { const f2 o = xb[r][pt_]; ar[r]=o.x; ai[r]=o.y; }
            }
        }
    }
}

__global__ __launch_bounds__(BLOCK) void vqc_kernel(
    const float* __restrict__ x,      // (1024, 12)
    const float* __restrict__ wts,    // (4, 12, 3)
    float* __restrict__ out)          // (1024, 12)
{
    __shared__ float gm[NL*NQ][8];
    __shared__ f2 xb[16][BLOCK];      // 32 KB exchange buffer [reg][tid]
    __shared__ float red[4][NQ];

    const int tid  = threadIdx.x;
    const int lane = tid & 63;
    const int wave = tid >> 6;
    const int b    = blockIdx.x;

    // ---- Rot gate matrices (batch-independent) ----
    if (tid < NL*NQ) {
        const float phi=wts[tid*3+0], th=wts[tid*3+1], om=wts[tid*3+2];
        const float ct=cosf(0.5f*th), sn=sinf(0.5f*th);
        float sp,cp,sd,cd;
        sincosf(0.5f*(phi+om), &sp, &cp);
        sincosf(0.5f*(phi-om), &sd, &cd);
        gm[tid][0]= cp*ct; gm[tid][1]=-sp*ct;   // g00 = em*ct
        gm[tid][2]=-cd*sn; gm[tid][3]=-sd*sn;   // g01 = -ed*sn
        gm[tid][4]= cd*sn; gm[tid][5]=-sd*sn;   // g10 = edc*sn
        gm[tid][6]= cp*ct; gm[tid][7]= sp*ct;   // g11 = ep*ct
    }
    __syncthreads();
    // ---- fuse AngleEmbedding RX into layer-0 Rot: G = Rot0 @ RX ----
    if (tid < NQ) {
        const float h = 0.5f * x[b*NQ + tid];
        const float c = cosf(h), s = sinf(h);
        const float R00r=gm[tid][0],R00i=gm[tid][1],R01r=gm[tid][2],R01i=gm[tid][3];
        const float R10r=gm[tid][4],R10i=gm[tid][5],R11r=gm[tid][6],R11i=gm[tid][7];
        // RX = [[c, -is],[-is, c]]
        gm[tid][0]=R00r*c+R01i*s; gm[tid][1]=R00i*c-R01r*s;
        gm[tid][2]=R00i*s+R01r*c; gm[tid][3]=R01i*c-R00r*s;
        gm[tid][4]=R10r*c+R11i*s; gm[tid][5]=R10i*c-R11r*s;
        gm[tid][6]=R10i*s+R11r*c; gm[tid][7]=R11i*c-R10r*s;
    }
    __syncthreads();

    // ---- state in registers ----
    float ar[16], ai[16];
#pragma unroll
    for (int r=0;r<16;++r){ ar[r]=0.f; ai[r]=0.f; }
    if (tid==0) ar[0]=1.f;

#define CN(c,t) cnot_gate<11-(c),11-(t)>(ar,ai,xb,tid,lane,wave)

#pragma unroll 1
    for (int l = 0; l < NL; ++l) {
        const float (*G)[8] = &gm[l*NQ];
        gate_wave<1>(ar,ai,xb,tid,wave,G[0]);   // q=0
        gate_wave<0>(ar,ai,xb,tid,wave,G[1]);   // q=1
        gate_lane<5>(ar,ai,lane,G[2]);
        gate_lane<4>(ar,ai,lane,G[3]);
        gate_lane<3>(ar,ai,lane,G[4]);
        gate_lane<2>(ar,ai,lane,G[5]);
        gate_lane<1>(ar,ai,lane,G[6]);
        gate_lane<0>(ar,ai,lane,G[7]);
        gate_local<3>(ar,ai,G[8]);
        gate_local<2>(ar,ai,G[9]);
        gate_local<1>(ar,ai,G[10]);
        gate_local<0>(ar,ai,G[11]);
        switch (l) {
        case 0: CN(0,1);CN(1,2);CN(2,3);CN(3,4);CN(4,5);CN(5,6);CN(6,7);CN(7,8);CN(8,9);CN(9,10);CN(10,11);CN(11,0); break;
        case 1: CN(0,2);CN(1,3);CN(2,4);CN(3,5);CN(4,6);CN(5,7);CN(6,8);CN(7,9);CN(8,10);CN(9,11);CN(10,0);CN(11,1); break;
        case 2: CN(0,3);CN(1,4);CN(2,5);CN(3,6);CN(4,7);CN(5,8);CN(6,9);CN(7,10);CN(8,11);CN(9,0);CN(10,1);CN(11,2); break;
        default:CN(0,4);CN(1,5);CN(2,6);CN(3,7);CN(4,8);CN(5,9);CN(6,10);CN(7,11);CN(8,0);CN(9,1);CN(10,2);CN(11,3); break;
        }
    }
#undef CN

    // ---- expectations ----
    float s=0.f, e8=0.f, e9=0.f, e10=0.f, e11=0.f;
#pragma unroll
    for (int r=0;r<16;++r){
        const float p = ar[r]*ar[r] + ai[r]*ai[r];
        s += p;
        e8  += ((r>>3)&1)? -p:p;
        e9  += ((r>>2)&1)? -p:p;
        e10 += ((r>>1)&1)? -p:p;
        e11 += ((r   )&1)? -p:p;
    }
    float ev[NQ];
    ev[0]=(wave&2)? -s:s;
    ev[1]=(wave&1)? -s:s;
#pragma unroll
    for (int q=2;q<8;++q) ev[q] = ((lane>>(7-q))&1)? -s:s;
    ev[8]=e8; ev[9]=e9; ev[10]=e10; ev[11]=e11;
#pragma unroll
    for (int q=0;q<NQ;++q)
#pragma unroll
        for (int off=32;off;off>>=1) ev[q] += __shfl_down(ev[q], off, 64);
    if (lane==0) {
#pragma unroll
        for (int q=0;q<NQ;++q) red[wave][q]=ev[q];
    }
    __syncthreads();
    if (tid < NQ) out[b*NQ+tid] = red[0][tid]+red[1][tid]+red[2][tid]+red[3][tid];
}

extern "C" void kernel_launch(void* const* d_in, const int* in_sizes, int n_in,
                              void* d_out, int out_size, void* d_ws, size_t ws_size,
                              hipStream_t stream) {
    const float* x   = (const float*)d_in[0];
    const float* wts = (const float*)d_in[1];
    float* out = (float*)d_out;
    vqc_kernel<<<dim3(NBATCH), dim3(BLOCK), 0, stream>>>(x, wts, out);
}